// Round 1
// baseline (59.140 us; speedup 1.0000x reference)
//
#include <hip/hip_runtime.h>

#define N_ 2
#define L_ 2048
#define H_ 8
#define NH_ 16
#define C_ 64
#define NC_ 32
#define EPS_ 1e-6f
#define DELTA_ 0.1f
#define STEP_ 1.0f

// workspace layout (floats)
#define SZ_KVS (NH_*NC_*4096)        // chunk KV sums -> exclusive prefix S0
#define OFF_KS (SZ_KVS)              // chunk k sums  -> exclusive prefix z0
#define SZ_KS  (NH_*NC_*64)
#define OFF_MU (OFF_KS + SZ_KS)      // mu[nh][L] (mu[L-1]=0)
#define OFF_AW (OFF_MU + NH_*L_)     // momentum weights a[nh][L]

__device__ __forceinline__ float elup1(float x) { return x > 0.f ? x + 1.f : __expf(x); }

// ---------------- Kernel A: per-chunk KV sums, k sums, mu ----------------
__global__ __launch_bounds__(256) void kA(const float* __restrict__ keys,
    const float* __restrict__ values, const float* __restrict__ mask,
    float* __restrict__ ws)
{
  float* kvs = ws;
  float* ks  = ws + OFF_KS;
  float* mu  = ws + OFF_MU;
  const int bid = blockIdx.x;
  const int c  = bid & (NC_-1);
  const int nh = bid >> 5;
  const int n = nh >> 3, h = nh & 7;
  const int tid = threadIdx.x;

  __shared__ __attribute__((aligned(16))) float Kl[65][68];
  __shared__ __attribute__((aligned(16))) float Vl[65][68];
  __shared__ float kpart[4][64];
  __shared__ float kkp[4][64], vvp[4][64], knp[4][64], vnp[4][64];
  __shared__ float kk[65], vv[65], kkn[64], vvn[64];

  // stage 65 rows (64 + 1 lookahead for mu at the chunk boundary)
  for (int idx = tid; idx < 65*64; idx += 256) {
    const int t = idx >> 6, e = idx & 63;
    const int l = c*C_ + t;
    float kx = 0.f, vx = 0.f;
    if (l < L_) {
      const size_t b = (((size_t)n*L_ + l)*H_ + h)*64 + e;
      kx = elup1(keys[b]) * mask[n*L_ + l];
      vx = values[b];
    }
    Kl[t][e] = kx; Vl[t][e] = vx;
  }
  __syncthreads();

  // chunk KV sum: 4x4 tile per thread
  {
    const int m4 = tid & 15, e4 = tid >> 4;
    float acc[4][4] = {{0.f}};
    for (int t = 0; t < 64; ++t) {
      const float4 k4 = *(const float4*)&Kl[t][e4*4];
      const float4 v4 = *(const float4*)&Vl[t][m4*4];
      const float ka[4] = {k4.x,k4.y,k4.z,k4.w};
      const float va[4] = {v4.x,v4.y,v4.z,v4.w};
      #pragma unroll
      for (int i = 0; i < 4; ++i)
        #pragma unroll
        for (int j = 0; j < 4; ++j) acc[i][j] += ka[i]*va[j];
    }
    float* outp = kvs + (size_t)bid*4096;
    #pragma unroll
    for (int i = 0; i < 4; ++i)
      *(float4*)&outp[(e4*4+i)*64 + m4*4] =
          make_float4(acc[i][0],acc[i][1],acc[i][2],acc[i][3]);
  }
  // k-sum partials
  {
    const int e = tid & 63, tq = tid >> 6;
    float s = 0.f;
    for (int t = tq*16; t < tq*16+16; ++t) s += Kl[t][e];
    kpart[tq][e] = s;
  }
  // mu dot-product partials over e-quarters
  {
    const int t = tid & 63, eq = tid >> 6;
    float a=0.f,b=0.f,cc2=0.f,d=0.f;
    for (int e = eq*16; e < eq*16+16; ++e) {
      const float k0 = Kl[t][e], k1 = Kl[t+1][e];
      const float v0 = Vl[t][e], v1 = Vl[t+1][e];
      a += k0*k0; b += v0*v0; cc2 += k0*k1; d += v0*v1;
    }
    kkp[eq][t]=a; vvp[eq][t]=b; knp[eq][t]=cc2; vnp[eq][t]=d;
  }
  // row-64 norms via wave reduce (wave 0)
  if (tid < 64) {
    const float kx = Kl[64][tid], vx = Vl[64][tid];
    float pk = kx*kx, pv = vx*vx;
    #pragma unroll
    for (int off = 32; off; off >>= 1) { pk += __shfl_down(pk, off); pv += __shfl_down(pv, off); }
    if (tid == 0) { kk[64] = pk; vv[64] = pv; }
  }
  __syncthreads();
  if (tid < 64) {
    ks[(size_t)bid*64 + tid] = kpart[0][tid]+kpart[1][tid]+kpart[2][tid]+kpart[3][tid];
    kk[tid]  = kkp[0][tid]+kkp[1][tid]+kkp[2][tid]+kkp[3][tid];
    vv[tid]  = vvp[0][tid]+vvp[1][tid]+vvp[2][tid]+vvp[3][tid];
    kkn[tid] = knp[0][tid]+knp[1][tid]+knp[2][tid]+knp[3][tid];
    vvn[tid] = vnp[0][tid]+vnp[1][tid]+vnp[2][tid]+vnp[3][tid];
  }
  __syncthreads();
  if (tid < 64) {
    const int j = c*C_ + tid;
    if (j < L_-1) {
      const float base2 = kk[tid]*vv[tid];
      float diff2 = kk[tid+1]*vv[tid+1] - 2.f*kkn[tid]*vvn[tid] + base2;
      diff2 = fmaxf(diff2, 0.f);
      const float r4 = sqrtf(sqrtf(diff2 / base2));
      float m = 1.f - r4; m = m*m;
      mu[(size_t)nh*L_ + j] = fminf(m, 1.f - DELTA_);
    } else {
      mu[(size_t)nh*L_ + j] = 0.f;
    }
  }
}

// ---------------- Kernel B: exclusive prefix over chunks (S0, z0) ----------------
__global__ __launch_bounds__(256) void kB(float* __restrict__ ws)
{
  const int id = blockIdx.x*256 + threadIdx.x;
  float* base; int stride;
  if (id < NH_*4096) {
    const int nh = id >> 12, elem = id & 4095;
    base = ws + (size_t)nh*NC_*4096 + elem;
    stride = 4096;
  } else {
    const int z = id - NH_*4096;           // 0..1023
    const int nh = z >> 6, e = z & 63;
    base = ws + OFF_KS + (size_t)nh*NC_*64 + e;
    stride = 64;
  }
  float acc = 0.f, cur = base[0];
  #pragma unroll 1
  for (int cc = 0; cc < NC_; ++cc) {
    const float nxt = (cc+1 < NC_) ? base[(size_t)(cc+1)*stride] : 0.f;
    base[(size_t)cc*stride] = acc;
    acc += cur;
    cur = nxt;
  }
}

// ---------------- Kernel C: backward affine scan for momentum weights ----------------
__global__ __launch_bounds__(256) void kC(float* __restrict__ ws)
{
  const int nh = blockIdx.x, tid = threadIdx.x;
  const float* mu = ws + OFF_MU + (size_t)nh*L_;
  float* aw = ws + OFF_AW + (size_t)nh*L_;
  __shared__ float P[256], Q[256];
  float lm[8];
  #pragma unroll
  for (int i = 0; i < 8; ++i) lm[i] = mu[tid*8 + i];
  float p = 1.f, q = 0.f;
  #pragma unroll
  for (int i = 7; i >= 0; --i) { q = lm[i]*q + 1.f; p *= lm[i]; }   // F = f_{j0} o ... o f_{j0+7}
  P[tid] = p; Q[tid] = q;
  __syncthreads();
  for (int d = 1; d < 256; d <<= 1) {                               // suffix scan of compositions
    float pr = 1.f, qr = 0.f;
    const bool has = (tid + d) < 256;
    if (has) { pr = P[tid+d]; qr = Q[tid+d]; }
    __syncthreads();
    if (has) { const float np = p*pr, nq = p*qr + q; p = np; q = nq; P[tid] = p; Q[tid] = q; }
    __syncthreads();
  }
  float x = (tid == 255) ? 1.f : P[tid+1] + Q[tid+1];               // a at segment end
  #pragma unroll
  for (int i = 7; i >= 0; --i) { x = lm[i]*x + 1.f; aw[tid*8+i] = x; }
}

// ---------------- Kernel D: per-chunk outputs (out + Kn) ----------------
__global__ __launch_bounds__(256) void kD(const float* __restrict__ queries,
    const float* __restrict__ keys, const float* __restrict__ values,
    const float* __restrict__ mask, const float* __restrict__ ws,
    float* __restrict__ out, float* __restrict__ kn)
{
  const float* kvs = ws;                  // exclusive prefix S0
  const float* ksx = ws + OFF_KS;         // exclusive prefix z0
  const float* aw  = ws + OFF_AW;
  const int bid = blockIdx.x;
  const int c = bid & (NC_-1), nh = bid >> 5, n = nh >> 3, h = nh & 7;
  const int tid = threadIdx.x;

  __shared__ __attribute__((aligned(16))) float Qt[64][68];  // [e][t]
  __shared__ __attribute__((aligned(16))) float Kt[64][68];  // [e][t]
  __shared__ __attribute__((aligned(16))) float At[64][68];  // [s][t]
  __shared__ float z0l[64], al[64], Zl[64], part[4][64];

  for (int idx = tid; idx < 4096; idx += 256) {
    const int t = idx >> 6, e = idx & 63;
    const int l = c*C_ + t;
    const size_t b = (((size_t)n*L_ + l)*H_ + h)*64 + e;
    Qt[e][t] = elup1(queries[b]);
    Kt[e][t] = elup1(keys[b]) * mask[n*L_ + l];
  }
  if (tid < 64) {
    z0l[tid] = ksx[(size_t)bid*64 + tid];
    al[tid]  = aw[(size_t)nh*L_ + c*C_ + tid];
  }
  __syncthreads();

  // QK^T -> At[s][t]
  {
    const int s4 = tid & 15, t4 = tid >> 4;
    float acc[4][4] = {{0.f}};
    for (int e = 0; e < 64; ++e) {
      const float4 q4 = *(const float4*)&Qt[e][t4*4];
      const float4 k4 = *(const float4*)&Kt[e][s4*4];
      const float qa[4] = {q4.x,q4.y,q4.z,q4.w};
      const float kb[4] = {k4.x,k4.y,k4.z,k4.w};
      #pragma unroll
      for (int i = 0; i < 4; ++i)
        #pragma unroll
        for (int j = 0; j < 4; ++j) acc[i][j] += qa[i]*kb[j];
    }
    #pragma unroll
    for (int j = 0; j < 4; ++j)
      *(float4*)&At[s4*4+j][t4*4] =
          make_float4(acc[0][j],acc[1][j],acc[2][j],acc[3][j]);
  }
  __syncthreads();

  // denominators: q_t . z0 + sum_{s<=t} A[t][s]
  {
    const int t = tid & 63, w = tid >> 6;
    float p = 0.f;
    for (int e = w*16; e < w*16+16; ++e) p += Qt[e][t]*z0l[e];
    for (int s = w*16; s < w*16+16; ++s) if (s <= t) p += At[s][t];
    part[w][t] = p;
  }
  __syncthreads();
  if (tid < 64)
    Zl[tid] = 1.f / (part[0][tid]+part[1][tid]+part[2][tid]+part[3][tid] + EPS_);

  // Kn = K * a * stepsize (coalesced on e)
  for (int idx = tid; idx < 4096; idx += 256) {
    const int t = idx >> 6, e = idx & 63;
    const int l = c*C_ + t;
    kn[(((size_t)n*L_ + l)*H_ + h)*64 + e] = Kt[e][t] * al[t] * STEP_;
  }
  __syncthreads();

  // out: thread owns column m for 16 t's
  {
    const int m = tid & 63, tg = tid >> 6;
    const float* S0 = kvs + (size_t)bid*4096;
    const float* vbase = values + (((size_t)n*L_ + c*C_)*H_ + h)*64 + m;
    float acc[16] = {0.f};
    // inter-chunk part: Q @ S0
    #pragma unroll 4
    for (int e = 0; e < 64; ++e) {
      const float s0 = S0[e*64 + m];
      #pragma unroll
      for (int k = 0; k < 4; ++k) {
        const float4 q4 = *(const float4*)&Qt[e][tg*16 + k*4];
        acc[k*4+0] += q4.x*s0; acc[k*4+1] += q4.y*s0;
        acc[k*4+2] += q4.z*s0; acc[k*4+3] += q4.w*s0;
      }
    }
    // intra-chunk, full rows s <= tg*16
    #pragma unroll 4
    for (int s = 0; s <= tg*16; ++s) {
      const float v = vbase[(size_t)s*H_*64];
      #pragma unroll
      for (int k = 0; k < 4; ++k) {
        const float4 a4 = *(const float4*)&At[s][tg*16 + k*4];
        acc[k*4+0] += a4.x*v; acc[k*4+1] += a4.y*v;
        acc[k*4+2] += a4.z*v; acc[k*4+3] += a4.w*v;
      }
    }
    // intra-chunk triangular tail (static indices via full unroll)
    #pragma unroll
    for (int i2 = 1; i2 < 16; ++i2) {
      const int s = tg*16 + i2;
      const float v = vbase[(size_t)s*H_*64];
      #pragma unroll
      for (int i = 0; i < 16; ++i)
        if (i >= i2) acc[i] += At[s][tg*16+i] * v;
    }
    #pragma unroll
    for (int i = 0; i < 16; ++i) {
      const int t = tg*16 + i;
      const int l = c*C_ + t;
      out[(((size_t)n*L_ + l)*H_ + h)*64 + m] = acc[i] * Zl[t];
    }
  }
}

extern "C" void kernel_launch(void* const* d_in, const int* in_sizes, int n_in,
                              void* d_out, int out_size, void* d_ws, size_t ws_size,
                              hipStream_t stream) {
  (void)in_sizes; (void)n_in; (void)out_size; (void)ws_size;
  const float* queries = (const float*)d_in[0];
  const float* keys    = (const float*)d_in[1];
  const float* values  = (const float*)d_in[2];
  const float* mask    = (const float*)d_in[3];
  float* out = (float*)d_out;
  float* kn  = out + (size_t)N_*L_*H_*64;
  float* ws  = (float*)d_ws;

  hipLaunchKernelGGL(kA, dim3(NH_*NC_), dim3(256), 0, stream, keys, values, mask, ws);
  hipLaunchKernelGGL(kB, dim3(260),     dim3(256), 0, stream, ws);
  hipLaunchKernelGGL(kC, dim3(NH_),     dim3(256), 0, stream, ws);
  hipLaunchKernelGGL(kD, dim3(NH_*NC_), dim3(256), 0, stream, queries, keys, values, mask, ws, out, kn);
}

// Round 2
// 36.238 us; speedup vs baseline: 1.6320x; 1.6320x over previous
//
#include <hip/hip_runtime.h>

#define N_ 2
#define L_ 2048
#define H_ 8
#define NH_ 16
#define C_ 64
#define NC_ 32
#define EPS_ 1e-6f
#define DELTA_ 0.1f

#define MWID 80                      // 64 v-cols + z-col(64) + pad
#define CHSZ (64*MWID)               // floats per chunk state
#define OFF_MU (NH_*NC_*CHSZ)
#define OFF_AW (OFF_MU + NH_*L_)

typedef short s8v __attribute__((ext_vector_type(8)));
typedef short s4v __attribute__((ext_vector_type(4)));
typedef float f4v __attribute__((ext_vector_type(4)));

__device__ __forceinline__ float elup1(float x){ return x>0.f ? x+1.f : __expf(x); }
__device__ __forceinline__ short f2b(float x){            // f32 -> bf16 RNE
  unsigned u = __float_as_uint(x);
  return (short)((u + 0x7FFFu + ((u>>16)&1u)) >> 16);
}

// ---------------- Kernel A: chunk state S_c = [K^T V | K^T 1] via MFMA, + mu (fp32) ----------------
__global__ __launch_bounds__(256) void kA(const float* __restrict__ keys,
    const float* __restrict__ values, const float* __restrict__ mask,
    float* __restrict__ ws)
{
  float* kvs = ws;
  float* mu  = ws + OFF_MU;
  const int bid = blockIdx.x, c = bid & (NC_-1), nh = bid >> 5;
  const int n = nh >> 3, h = nh & 7, tid = threadIdx.x;

  __shared__ __attribute__((aligned(16))) float Klf[65][68];   // fp32 for mu
  __shared__ __attribute__((aligned(16))) float Vlf[65][68];
  __shared__ __attribute__((aligned(16))) short Ktb[64][72];   // bf16 [e][t]
  __shared__ __attribute__((aligned(16))) short Vtb[80][72];   // bf16 [m][t], row64=1s
  __shared__ float kkp[4][64], vvp[4][64], knp[4][64], vnp[4][64];
  __shared__ float kk[65], vv[65], kkn[64], vvn[64];

  for (int idx = tid; idx < 65*64; idx += 256) {
    const int t = idx >> 6, e = idx & 63, l = c*C_ + t;
    float kx = 0.f, vx = 0.f;
    if (l < L_) {
      const size_t b = (((size_t)n*L_ + l)*H_ + h)*64 + e;
      kx = elup1(keys[b]) * mask[n*L_ + l];
      vx = values[b];
    }
    Klf[t][e] = kx; Vlf[t][e] = vx;
    if (t < 64) { Ktb[e][t] = f2b(kx); Vtb[e][t] = f2b(vx); }
  }
  for (int idx = tid; idx < 16*72; idx += 256) {
    const int rr = idx/72, cc = idx - rr*72;
    Vtb[64+rr][cc] = (rr==0 && cc<64) ? f2b(1.f) : (short)0;
  }
  __syncthreads();

  // S[e][m] = sum_t K[t][e]*Vaug[t][m]  (M=e, N=m, K=t)
  {
    const int lane = tid & 63, w = tid >> 6, r = lane & 15, g = lane >> 4;
    f4v acc[5];
    #pragma unroll
    for (int j = 0; j < 5; ++j) acc[j] = (f4v)(0.f);
    #pragma unroll
    for (int kk2 = 0; kk2 < 2; ++kk2) {
      const s8v a = *(const s8v*)&Ktb[w*16 + r][kk2*32 + g*8];
      #pragma unroll
      for (int mj = 0; mj < 5; ++mj) {
        const s8v b = *(const s8v*)&Vtb[mj*16 + r][kk2*32 + g*8];
        acc[mj] = __builtin_amdgcn_mfma_f32_16x16x32_bf16(a, b, acc[mj], 0, 0, 0);
      }
    }
    float* outp = kvs + (size_t)bid*CHSZ;
    #pragma unroll
    for (int mj = 0; mj < 5; ++mj)
      #pragma unroll
      for (int j = 0; j < 4; ++j)
        outp[(w*16 + g*4 + j)*MWID + mj*16 + r] = acc[mj][j];
  }

  // mu partials (fp32, exact as round 0)
  {
    const int t = tid & 63, eq = tid >> 6;
    float a=0.f,b=0.f,c2=0.f,d=0.f;
    for (int e = eq*16; e < eq*16+16; ++e) {
      const float k0 = Klf[t][e], k1 = Klf[t+1][e];
      const float v0 = Vlf[t][e], v1 = Vlf[t+1][e];
      a += k0*k0; b += v0*v0; c2 += k0*k1; d += v0*v1;
    }
    kkp[eq][t]=a; vvp[eq][t]=b; knp[eq][t]=c2; vnp[eq][t]=d;
  }
  if (tid < 64) {
    const float kx = Klf[64][tid], vx = Vlf[64][tid];
    float pk = kx*kx, pv = vx*vx;
    #pragma unroll
    for (int off = 32; off; off >>= 1) { pk += __shfl_down(pk, off); pv += __shfl_down(pv, off); }
    if (tid == 0) { kk[64] = pk; vv[64] = pv; }
  }
  __syncthreads();
  if (tid < 64) {
    kk[tid]  = kkp[0][tid]+kkp[1][tid]+kkp[2][tid]+kkp[3][tid];
    vv[tid]  = vvp[0][tid]+vvp[1][tid]+vvp[2][tid]+vvp[3][tid];
    kkn[tid] = knp[0][tid]+knp[1][tid]+knp[2][tid]+knp[3][tid];
    vvn[tid] = vnp[0][tid]+vnp[1][tid]+vnp[2][tid]+vnp[3][tid];
  }
  __syncthreads();
  if (tid < 64) {
    const int j = c*C_ + tid;
    if (j < L_-1) {
      const float base2 = kk[tid]*vv[tid];
      float diff2 = kk[tid+1]*vv[tid+1] - 2.f*kkn[tid]*vvn[tid] + base2;
      diff2 = fmaxf(diff2, 0.f);
      const float r4 = sqrtf(sqrtf(diff2 / base2));
      float m = 1.f - r4; m = m*m;
      mu[(size_t)nh*L_ + j] = fminf(m, 1.f - DELTA_);
    } else {
      mu[(size_t)nh*L_ + j] = 0.f;
    }
  }
}

// ------- Kernel BC: register-batched exclusive chunk prefix + momentum suffix scan -------
__global__ __launch_bounds__(256) void kBC(float* __restrict__ ws)
{
  const int bx = blockIdx.x, tid = threadIdx.x;
  if (bx < 320) {                                    // prefix over chunks, 16*CHSZ lanes
    const int id = bx*256 + tid;
    const int nh = id / CHSZ, elem = id - nh*CHSZ;
    float* base = ws + (size_t)nh*NC_*CHSZ + elem;
    float r[32];
    #pragma unroll
    for (int cc = 0; cc < 32; ++cc) r[cc] = base[(size_t)cc*CHSZ];
    float acc = 0.f;
    #pragma unroll
    for (int cc = 0; cc < 32; ++cc) { const float t = r[cc]; base[(size_t)cc*CHSZ] = acc; acc += t; }
    return;
  }
  // momentum weights: a_j = 1 + mu_j * a_{j+1}, suffix scan of affine maps
  const int nh = bx - 320;
  const float* mu = ws + OFF_MU + (size_t)nh*L_;
  float* aw = ws + OFF_AW + (size_t)nh*L_;
  __shared__ float P[256], Q[256];
  float lm[8];
  #pragma unroll
  for (int i = 0; i < 8; ++i) lm[i] = mu[tid*8 + i];
  float p = 1.f, q = 0.f;
  #pragma unroll
  for (int i = 7; i >= 0; --i) { q = lm[i]*q + 1.f; p *= lm[i]; }
  P[tid] = p; Q[tid] = q;
  __syncthreads();
  for (int d = 1; d < 256; d <<= 1) {
    float pr = 1.f, qr = 0.f;
    const bool has = (tid + d) < 256;
    if (has) { pr = P[tid+d]; qr = Q[tid+d]; }
    __syncthreads();
    if (has) { const float np = p*pr, nq = p*qr + q; p = np; q = nq; P[tid] = p; Q[tid] = q; }
    __syncthreads();
  }
  float x = (tid == 255) ? 1.f : P[tid+1] + Q[tid+1];
  #pragma unroll
  for (int i = 7; i >= 0; --i) { x = lm[i]*x + 1.f; aw[tid*8+i] = x; }
}

// ---------------- Kernel D: QK^T + fused [Q|P]x[S0;Vaug] GEMM via MFMA ----------------
__global__ __launch_bounds__(256) void kD(const float* __restrict__ queries,
    const float* __restrict__ keys, const float* __restrict__ values,
    const float* __restrict__ mask, const float* __restrict__ ws,
    float* __restrict__ out, float* __restrict__ kn)
{
  const float* kvs = ws;
  const float* aw  = ws + OFF_AW;
  const int bid = blockIdx.x, c = bid & (NC_-1), nh = bid >> 5;
  const int n = nh >> 3, h = nh & 7, tid = threadIdx.x;
  const int lane = tid & 63, w = tid >> 6, r = lane & 15, g = lane >> 4;

  __shared__ __attribute__((aligned(16))) short Qb[64][72];    // bf16 [t][e]
  __shared__ __attribute__((aligned(16))) short Kb[64][72];    // bf16 [s][e]
  __shared__ __attribute__((aligned(16))) short Pb[64][72];    // bf16 [t][s], causal-masked
  __shared__ __attribute__((aligned(16))) short SV[2][80][72]; // [0]=S0t [m][e], [1]=Vaug^T [m][s]
  __shared__ float Zl[64], al[64];
  short (*Sb)[72] = SV[0];
  short (*Vt)[72] = SV[1];
  float (*outf)[68] = (float (*)[68])(void*)SV;                // aliases SV after GEMM

  for (int idx = tid; idx < 4096; idx += 256) {
    const int t = idx >> 6, e = idx & 63, l = c*C_ + t;
    const size_t b = (((size_t)n*L_ + l)*H_ + h)*64 + e;
    const float m0 = mask[n*L_ + l];
    Qb[t][e] = f2b(elup1(queries[b]));
    Kb[t][e] = f2b(elup1(keys[b]) * m0);
    Vt[e][t] = f2b(values[b]);
  }
  for (int idx = tid; idx < 16*72; idx += 256) {
    const int rr = idx/72, cc = idx - rr*72;
    Vt[64+rr][cc] = (rr==0 && cc<64) ? f2b(1.f) : (short)0;
  }
  for (int idx = tid; idx < CHSZ; idx += 256) {
    const int e = idx / MWID, m = idx - e*MWID;
    Sb[m][e] = f2b(kvs[(size_t)bid*CHSZ + idx]);
  }
  if (tid < 64) al[tid] = aw[(size_t)nh*L_ + c*C_ + tid];
  __syncthreads();

  // Phase 1: QK^T (M=s, N=t, K=e) -> Pb[t][s] bf16, causal-masked
  {
    f4v pacc[4];
    #pragma unroll
    for (int j = 0; j < 4; ++j) pacc[j] = (f4v)(0.f);
    #pragma unroll
    for (int kk2 = 0; kk2 < 2; ++kk2) {
      const s8v a = *(const s8v*)&Kb[w*16 + r][kk2*32 + g*8];
      #pragma unroll
      for (int tj = 0; tj < 4; ++tj) {
        const s8v b = *(const s8v*)&Qb[tj*16 + r][kk2*32 + g*8];
        pacc[tj] = __builtin_amdgcn_mfma_f32_16x16x32_bf16(a, b, pacc[tj], 0, 0, 0);
      }
    }
    #pragma unroll
    for (int tj = 0; tj < 4; ++tj) {
      const int t = tj*16 + r;
      s4v pk;
      #pragma unroll
      for (int j = 0; j < 4; ++j) {
        const int s = w*16 + g*4 + j;
        pk[j] = (s <= t) ? f2b(pacc[tj][j]) : (short)0;
      }
      *(s4v*)&Pb[t][w*16 + g*4] = pk;
    }
  }
  __syncthreads();

  // Phase 2: out_aug[t][m] = sum_e Q[t][e] S0[e][m] + sum_s P[t][s] Vaug[s][m], col 64 = denom
  f4v oacc[5];
  #pragma unroll
  for (int j = 0; j < 5; ++j) oacc[j] = (f4v)(0.f);
  #pragma unroll
  for (int kk2 = 0; kk2 < 4; ++kk2) {
    const s8v a = (kk2 < 2) ? *(const s8v*)&Qb[w*16 + r][kk2*32 + g*8]
                            : *(const s8v*)&Pb[w*16 + r][(kk2-2)*32 + g*8];
    #pragma unroll
    for (int mj = 0; mj < 5; ++mj) {
      const s8v b = (kk2 < 2) ? *(const s8v*)&Sb[mj*16 + r][kk2*32 + g*8]
                              : *(const s8v*)&Vt[mj*16 + r][(kk2-2)*32 + g*8];
      oacc[mj] = __builtin_amdgcn_mfma_f32_16x16x32_bf16(a, b, oacc[mj], 0, 0, 0);
    }
  }
  __syncthreads();                       // SV reads done; safe to alias as outf

  if (r == 0) {
    #pragma unroll
    for (int j = 0; j < 4; ++j) Zl[w*16 + g*4 + j] = 1.f / (oacc[4][j] + EPS_);
  }
  #pragma unroll
  for (int mj = 0; mj < 4; ++mj)
    #pragma unroll
    for (int j = 0; j < 4; ++j)
      outf[w*16 + g*4 + j][mj*16 + r] = oacc[mj][j];
  __syncthreads();

  // out store (vectorized) + Kn (exact fp32 path)
  for (int idx = tid; idx < 1024; idx += 256) {
    const int t = idx >> 4, m4 = idx & 15, l = c*C_ + t;
    f4v v = *(const f4v*)&outf[t][m4*4];
    v *= Zl[t];
    *(f4v*)&out[(((size_t)n*L_ + l)*H_ + h)*64 + m4*4] = v;
  }
  for (int idx = tid; idx < 1024; idx += 256) {
    const int t = idx >> 4, e4 = idx & 15, l = c*C_ + t;
    const size_t b = (((size_t)n*L_ + l)*H_ + h)*64 + e4*4;
    const float m0 = mask[n*L_ + l] * al[t];
    const f4v kx = *(const f4v*)&keys[b];
    f4v o;
    o[0] = elup1(kx[0])*m0; o[1] = elup1(kx[1])*m0;
    o[2] = elup1(kx[2])*m0; o[3] = elup1(kx[3])*m0;
    *(f4v*)&kn[b] = o;
  }
}

extern "C" void kernel_launch(void* const* d_in, const int* in_sizes, int n_in,
                              void* d_out, int out_size, void* d_ws, size_t ws_size,
                              hipStream_t stream) {
  (void)in_sizes; (void)n_in; (void)out_size; (void)ws_size;
  const float* queries = (const float*)d_in[0];
  const float* keys    = (const float*)d_in[1];
  const float* values  = (const float*)d_in[2];
  const float* mask    = (const float*)d_in[3];
  float* out = (float*)d_out;
  float* kn  = out + (size_t)N_*L_*H_*64;
  float* ws  = (float*)d_ws;

  hipLaunchKernelGGL(kA,  dim3(NH_*NC_), dim3(256), 0, stream, keys, values, mask, ws);
  hipLaunchKernelGGL(kBC, dim3(336),     dim3(256), 0, stream, ws);
  hipLaunchKernelGGL(kD,  dim3(NH_*NC_), dim3(256), 0, stream, queries, keys, values, mask, ws, out, kn);
}